// Round 1
// 570.613 us; speedup vs baseline: 1.1813x; 1.1813x over previous
//
#include <hip/hip_runtime.h>
#include <hip/hip_fp16.h>
#include <cstdint>

// B=8, S=4096, D=1024, window +-128, out fp32.
// Pipeline: cvt x->fp16; cvt+transpose W->fp16; QKV MFMA GEMM; banded
// QK^T+softmax -> P fp16; banded PV -> fp32 out.
//
// R3: QKV GEMM rewritten as fused-N (N=3072) 256x256-tile 8-phase schedule
// (learn_hip m201 template): 512 thr / 8 waves (2Mx4N), BK=64, 128KiB LDS
// double-buffer, XOR-octet swizzle (kept from R2 - bank conflicts were 0),
// counted s_waitcnt vmcnt(4) at phase 4 only (loads stay in flight across
// barriers), s_setprio(1) around each 16-MFMA cluster.
// Slot-death schedule (per K-tile t, buffers by t&1):
//   P1: dsread A0+B0 (12) | stage A0(t+1)   [slot dead since t-1.P3]
//   P2: dsread B1    (4)  | stage A1(t+1)   [dead since t-1.P3]
//   P3: dsread A1    (8)  | stage B0(t+2)   [dead after t.P2]
//   P4: (regs only)       | stage B1(t+2)   [dead after t.P2] ; vmcnt(4)
// vmcnt(4) at t.P4 leaves only B0/B1(t+2) outstanding -> tile t+1 fully
// staged before its P1 ds_reads. 2 half-tiles always in flight.
//
// Workspace (halves): xh[33554432] | wt[3*1048576] | qh[33554432] |
// kh[33554432] | v8[33554432]  (P aliases xh, dead after GEMM1)

#define DEV __device__ __forceinline__

typedef _Float16 f16x8 __attribute__((ext_vector_type(8)));
typedef _Float16 f16x4 __attribute__((ext_vector_type(4)));
typedef float    f32x4 __attribute__((ext_vector_type(4)));

DEV _Float16 f2h(float f) { return (_Float16)f; }

DEV void gl16(const void* g, void* l) {
  __builtin_amdgcn_global_load_lds(
      (const __attribute__((address_space(1))) void*)(uintptr_t)g,
      (__attribute__((address_space(3))) void*)(uintptr_t)l, 16, 0, 0);
}

#define MFMA16(a, b, c) __builtin_amdgcn_mfma_f32_16x16x32_f16((a), (b), (c), 0, 0, 0)

// ---------------- convert x (fp32 -> fp16), 8 elems/thread ----------------
__global__ __launch_bounds__(256) void k_cvt_x(const float* __restrict__ x,
                                               _Float16* __restrict__ xh) {
  size_t i = ((size_t)blockIdx.x * 256 + threadIdx.x) * 8;
  float4 f0 = *(const float4*)(x + i);
  float4 f1 = *(const float4*)(x + i + 4);
  f16x8 o;
  o[0] = f2h(f0.x); o[1] = f2h(f0.y); o[2] = f2h(f0.z); o[3] = f2h(f0.w);
  o[4] = f2h(f1.x); o[5] = f2h(f1.y); o[6] = f2h(f1.z); o[7] = f2h(f1.w);
  *(f16x8*)(xh + i) = o;
}

// ------------- transpose+convert W [k][n] fp32 -> Wt [n][k] fp16 -------------
__global__ __launch_bounds__(256) void k_cvt_w(const float* __restrict__ Wq,
                                               const float* __restrict__ Wk,
                                               const float* __restrict__ Wv,
                                               _Float16* __restrict__ wt) {
  __shared__ float tile[64][65];
  const int z = blockIdx.z;
  const int n0 = blockIdx.x * 64, k0 = blockIdx.y * 64;
  const float* W = (z == 0) ? Wq : (z == 1) ? Wk : Wv;
  const int tid = threadIdx.x;
  const int r0 = tid >> 4;           // 0..15
  const int c4 = (tid & 15) * 4;     // 0..60
#pragma unroll
  for (int rr = 0; rr < 4; ++rr) {
    int r = r0 + rr * 16;
    float4 v = *(const float4*)(W + (size_t)(k0 + r) * 1024 + n0 + c4);
    tile[r][c4 + 0] = v.x; tile[r][c4 + 1] = v.y;
    tile[r][c4 + 2] = v.z; tile[r][c4 + 3] = v.w;
  }
  __syncthreads();
  _Float16* out = wt + (size_t)z * 1048576;
#pragma unroll
  for (int rr = 0; rr < 4; ++rr) {
    int n = r0 + rr * 16;
    f16x4 o;
#pragma unroll
    for (int jj = 0; jj < 4; ++jj) o[jj] = f2h(tile[c4 + jj][n]);
    *(f16x4*)(out + (size_t)(n0 + n) * 1024 + k0 + c4) = o;
  }
}

// ---- QKV GEMM: [32768x1024] x Wt^T (N=3072 fused), 256x256 tile, 8-phase ----
__global__ __launch_bounds__(512, 2) void k_gemm_qkv(
    const _Float16* __restrict__ xh, const _Float16* __restrict__ wt,
    const float* __restrict__ bq, const float* __restrict__ bk,
    const float* __restrict__ bv, _Float16* __restrict__ qh,
    _Float16* __restrict__ kh, _Float16* __restrict__ v8) {
  // LDS: [buf 0/1][ A 256x64 | B 256x64 ] halves; 131072 bytes total.
  __shared__ _Float16 L[65536];

  // XCD-aware swizzle: 1536 blocks, 1536 % 8 == 0 -> simple bijective remap.
  const int bid = blockIdx.x;
  const int wg = (bid & 7) * 192 + (bid >> 3);
  const int mt = wg / 12, nt = wg % 12;   // 128 m-tiles x 12 n-tiles
  const int gm0 = mt * 256;
  const int gn0 = nt * 256;               // global n in [0,3072)

  const int tid = threadIdx.x;
  const int w = tid >> 6, l = tid & 63;   // 8 waves
  const int ln = l & 15, quad = l >> 4;
  const int wm = w >> 2, wn = w & 3;      // 2x4 wave grid, 128x64 out each
  const int lr = l >> 3;                  // 0..7
  const int kc = ((l & 7) ^ lr) * 8;      // pre-swizzled source k-column
  const int swz = ln & 7;                 // fragment-read octet xor

  // stage one 128x64 half-tile (2 x global_load_lds per thread)
  auto stageA = [&](int it, int h) {
    const _Float16* src =
        xh + (size_t)(gm0 + h * 128 + w * 8 + lr) * 1024 + it * 64 + kc;
    _Float16* dst = L + (it & 1) * 32768 + (h * 128 + w * 8) * 64;
    gl16(src, dst);
    gl16(src + 64 * 1024, dst + 64 * 64);
  };
  auto stageB = [&](int it, int h) {
    const _Float16* src =
        wt + (size_t)(gn0 + h * 128 + w * 8 + lr) * 1024 + it * 64 + kc;
    _Float16* dst = L + (it & 1) * 32768 + 16384 + (h * 128 + w * 8) * 64;
    gl16(src, dst);
    gl16(src + 64 * 1024, dst + 64 * 64);
  };

#define RD(base, r, ko) \
  (*(const f16x8*)((base) + (size_t)(r) * 64 + (((ko) ^ swz) * 8)))

  f32x4 acc[8][4] = {};
  f16x8 aA[2][4], bb0[2][2], bb1[2][2];

  // Prologue: tile0 fully + B halves of tile1; wait first 8 loads (tile0).
  stageA(0, 0); stageA(0, 1); stageB(0, 0); stageB(0, 1);
  stageB(1, 0); stageB(1, 1);
  asm volatile("s_waitcnt vmcnt(4)" ::: "memory");
  __builtin_amdgcn_s_barrier();

#pragma unroll 2
  for (int t = 0; t < 16; ++t) {
    const _Float16* Ab = L + (t & 1) * 32768;
    const _Float16* Bb = Ab + 16384;
    const int rA = wm * 128 + ln;
    const int rB = wn * 64 + ln;

    // ---------------- P1: A0+B0 reads | stage A0(t+1) | MFMA Q00 ----------------
#pragma unroll
    for (int i = 0; i < 4; ++i) {
      aA[0][i] = RD(Ab, rA + i * 16, quad);
      aA[1][i] = RD(Ab, rA + i * 16, quad + 4);
    }
#pragma unroll
    for (int j = 0; j < 2; ++j) {
      bb0[0][j] = RD(Bb, rB + j * 16, quad);
      bb0[1][j] = RD(Bb, rB + j * 16, quad + 4);
    }
    if (t + 1 < 16) stageA(t + 1, 0);
    __builtin_amdgcn_s_barrier();
    asm volatile("s_waitcnt lgkmcnt(0)" ::: "memory");
    __builtin_amdgcn_sched_barrier(0);
    __builtin_amdgcn_s_setprio(1);
#pragma unroll
    for (int s = 0; s < 2; ++s)
#pragma unroll
      for (int i = 0; i < 4; ++i)
#pragma unroll
        for (int j = 0; j < 2; ++j)
          acc[i][j] = MFMA16(aA[s][i], bb0[s][j], acc[i][j]);
    __builtin_amdgcn_s_setprio(0);
    __builtin_amdgcn_s_barrier();

    // ---------------- P2: B1 reads | stage A1(t+1) | MFMA Q01 ----------------
#pragma unroll
    for (int j = 0; j < 2; ++j) {
      bb1[0][j] = RD(Bb, rB + 32 + j * 16, quad);
      bb1[1][j] = RD(Bb, rB + 32 + j * 16, quad + 4);
    }
    if (t + 1 < 16) stageA(t + 1, 1);
    __builtin_amdgcn_s_barrier();
    asm volatile("s_waitcnt lgkmcnt(0)" ::: "memory");
    __builtin_amdgcn_sched_barrier(0);
    __builtin_amdgcn_s_setprio(1);
#pragma unroll
    for (int s = 0; s < 2; ++s)
#pragma unroll
      for (int i = 0; i < 4; ++i)
#pragma unroll
        for (int j = 0; j < 2; ++j)
          acc[i][2 + j] = MFMA16(aA[s][i], bb1[s][j], acc[i][2 + j]);
    __builtin_amdgcn_s_setprio(0);
    __builtin_amdgcn_s_barrier();

    // ---------------- P3: A1 reads | stage B0(t+2) | MFMA Q11 ----------------
#pragma unroll
    for (int i = 0; i < 4; ++i) {
      aA[0][i] = RD(Ab, rA + 64 + i * 16, quad);
      aA[1][i] = RD(Ab, rA + 64 + i * 16, quad + 4);
    }
    if (t + 2 < 16) stageB(t + 2, 0);
    __builtin_amdgcn_s_barrier();
    asm volatile("s_waitcnt lgkmcnt(0)" ::: "memory");
    __builtin_amdgcn_sched_barrier(0);
    __builtin_amdgcn_s_setprio(1);
#pragma unroll
    for (int s = 0; s < 2; ++s)
#pragma unroll
      for (int i = 0; i < 4; ++i)
#pragma unroll
        for (int j = 0; j < 2; ++j)
          acc[4 + i][2 + j] = MFMA16(aA[s][i], bb1[s][j], acc[4 + i][2 + j]);
    __builtin_amdgcn_s_setprio(0);
    __builtin_amdgcn_s_barrier();

    // ------------- P4: (regs only) | stage B1(t+2) | MFMA Q10 | vmcnt -------------
    if (t + 2 < 16) stageB(t + 2, 1);
    __builtin_amdgcn_s_setprio(1);
#pragma unroll
    for (int s = 0; s < 2; ++s)
#pragma unroll
      for (int i = 0; i < 4; ++i)
#pragma unroll
        for (int j = 0; j < 2; ++j)
          acc[4 + i][j] = MFMA16(aA[s][i], bb0[s][j], acc[4 + i][j]);
    __builtin_amdgcn_s_setprio(0);
    if (t + 2 < 16)
      asm volatile("s_waitcnt vmcnt(4)" ::: "memory");
    else
      asm volatile("s_waitcnt vmcnt(0)" ::: "memory");
    __builtin_amdgcn_s_barrier();
  }
#undef RD

  // Epilogue: z from fused-n (each 256-tile entirely within one z).
  const int z2 = gn0 >> 10;
  const int colz = (gn0 & 1023) + wn * 64;
  const int row0 = gm0 + wm * 128;
  if (z2 != 2) {
    const float* bias = z2 ? bk : bq;
    _Float16* outp = z2 ? kh : qh;
#pragma unroll
    for (int j = 0; j < 4; ++j) {
      float bb = bias[colz + j * 16 + ln];
#pragma unroll
      for (int i = 0; i < 8; ++i) {
        int row = row0 + i * 16 + quad * 4;
        size_t base = (size_t)row * 1024 + colz + j * 16 + ln;
#pragma unroll
        for (int r = 0; r < 4; ++r)
          outp[base + (size_t)r * 1024] = f2h(acc[i][j][r] + bb);
      }
    }
  } else {
    // V in 8-inner layout: v8[(row/8)*8192 + col*8 + row%8]
#pragma unroll
    for (int j = 0; j < 4; ++j) {
      float bb = bv[colz + j * 16 + ln];
#pragma unroll
      for (int i = 0; i < 8; ++i) {
        int rr = row0 + i * 16 + quad * 4;  // 4 consecutive rows
        int col = colz + j * 16 + ln;
        f16x4 o;
#pragma unroll
        for (int r = 0; r < 4; ++r) o[r] = f2h(acc[i][j][r] + bb);
        *(f16x4*)(v8 + (size_t)(rr >> 3) * 8192 + (size_t)col * 8 + (rr & 7)) = o;
      }
    }
  }
}

// -------- banded scores + softmax: per (tile of 64 q, batch) -> P fp16 --------
__global__ __launch_bounds__(256) void k_scores(const _Float16* __restrict__ qh,
                                                const _Float16* __restrict__ kh,
                                                _Float16* __restrict__ ph) {
  __shared__ _Float16 lQ[64 * 64];
  __shared__ _Float16 lK[320 * 64];
  const int t = blockIdx.x, b = blockIdx.y;
  const int i0 = t * 64, k0 = i0 - 128;
  const int tid = threadIdx.x, w = tid >> 6, l = tid & 63;
  const int ln = l & 15, quad = l >> 4;
  const _Float16* qrow = qh + (size_t)b * 4096 * 1024;
  const _Float16* krow = kh + (size_t)b * 4096 * 1024;
  const int kc = (((l & 7) ^ (l >> 3)) * 8);
  const int swz = ln & 7;

  f32x4 acc[20] = {};

  for (int it = 0; it < 16; ++it) {
#pragma unroll
    for (int c = 0; c < 2; ++c) {
      int cid = w * 2 + c;
      int rl = cid * 8 + (l >> 3);
      gl16(qrow + (size_t)(i0 + rl) * 1024 + it * 64 + kc, lQ + cid * 512);
    }
#pragma unroll
    for (int c = 0; c < 10; ++c) {
      int cid = w * 10 + c;
      int rl = cid * 8 + (l >> 3);
      int gr = k0 + rl;
      gr = min(max(gr, 0), 4095);  // clamped rows are masked below
      gl16(krow + (size_t)gr * 1024 + it * 64 + kc, lK + cid * 512);
    }
    __builtin_amdgcn_s_waitcnt(0);
    __syncthreads();
#pragma unroll
    for (int kk = 0; kk < 64; kk += 32) {
      f16x8 a = *(const f16x8*)(lQ + (w * 16 + ln) * 64 +
                                (((kk >> 3) + quad) ^ swz) * 8);
#pragma unroll
      for (int j = 0; j < 20; ++j) {
        f16x8 bf = *(const f16x8*)(lK + (j * 16 + ln) * 64 +
                                   (((kk >> 3) + quad) ^ swz) * 8);
        acc[j] = MFMA16(a, bf, acc[j]);
      }
    }
    __syncthreads();
  }

  // mask + softmax (C-layout: col=j*16+ln, row=w*16+quad*4+r)
  const float scale = 0.03125f;  // 1/sqrt(1024)
  float mrow[4] = {-1e30f, -1e30f, -1e30f, -1e30f};
#pragma unroll
  for (int j = 0; j < 20; ++j) {
    int jc = k0 + j * 16 + ln;
    bool cval = (jc >= 0) && (jc < 4096);
#pragma unroll
    for (int r = 0; r < 4; ++r) {
      int i = i0 + w * 16 + quad * 4 + r;
      int rel = jc - i;
      bool val = cval && (rel >= -128) && (rel <= 128);
      float s = val ? acc[j][r] * scale : -1e30f;
      acc[j][r] = s;
      mrow[r] = fmaxf(mrow[r], s);
    }
  }
#pragma unroll
  for (int r = 0; r < 4; ++r)
#pragma unroll
    for (int m = 1; m < 16; m <<= 1) mrow[r] = fmaxf(mrow[r], __shfl_xor(mrow[r], m));
  float sum[4] = {0.f, 0.f, 0.f, 0.f};
#pragma unroll
  for (int j = 0; j < 20; ++j)
#pragma unroll
    for (int r = 0; r < 4; ++r) {
      float e = __builtin_exp2f((acc[j][r] - mrow[r]) * 1.44269504f);
      acc[j][r] = e;
      sum[r] += e;
    }
#pragma unroll
  for (int r = 0; r < 4; ++r) {
#pragma unroll
    for (int m = 1; m < 16; m <<= 1) sum[r] += __shfl_xor(sum[r], m);
    sum[r] = 1.0f / sum[r];
  }
  _Float16* pt = ph + (size_t)(b * 64 + t) * 64 * 320;
#pragma unroll
  for (int j = 0; j < 20; ++j)
#pragma unroll
    for (int r = 0; r < 4; ++r)
      pt[(size_t)(w * 16 + quad * 4 + r) * 320 + j * 16 + ln] = f2h(acc[j][r] * sum[r]);
}

// ---------------- PV: out[64 x 256] = P[64 x 320] * V[320 x 256] ----------------
__global__ __launch_bounds__(256) void k_pv(const _Float16* __restrict__ ph,
                                            const _Float16* __restrict__ v8,
                                            float* __restrict__ out) {
  __shared__ _Float16 lP[64 * 40];      // rows padded 32 -> 40 (bank spread)
  __shared__ _Float16 lV[4 * 256 * 8];  // [k-octet][n][8]
  const int nc = blockIdx.x, t = blockIdx.y, b = blockIdx.z;
  const int n0 = nc * 256;
  const int tid = threadIdx.x, w = tid >> 6, l = tid & 63;
  const int ln = l & 15, quad = l >> 4;
  const _Float16* pt = ph + (size_t)(b * 64 + t) * 64 * 320;
  const _Float16* vb = v8 + (size_t)b * 4194304;
  const int k0 = t * 64 - 128;

  f32x4 acc[16] = {};

  for (int it = 0; it < 10; ++it) {
    int kk = it * 32;
    if (it) __syncthreads();
    {  // stage P tile [64][32]: 256 threads x 8 halves = 2048 halves (full tile)
      int row = tid >> 2, ch = tid & 3;
      f16x8 d = *(const f16x8*)(pt + (size_t)row * 320 + kk + ch * 8);
      *(f16x8*)(lP + row * 40 + ch * 8) = d;
    }
#pragma unroll
    for (int c = 0; c < 4; ++c) {  // stage V [4 octets][256 n][8]
      int nloc = w * 64 + l;
      int g = ((k0 + kk) >> 3) + c;
      g = min(max(g, 0), 511);  // P==0 on clamped keys
      gl16(vb + (size_t)g * 8192 + (size_t)(n0 + nloc) * 8, lV + (c * 256 + w * 64) * 8);
    }
    __builtin_amdgcn_s_waitcnt(0);
    __syncthreads();
    f16x8 a = *(const f16x8*)(lP + (w * 16 + ln) * 40 + quad * 8);
#pragma unroll
    for (int j = 0; j < 16; ++j) {
      f16x8 bv = *(const f16x8*)(lV + (quad * 256 + j * 16 + ln) * 8);
      acc[j] = MFMA16(a, bv, acc[j]);
    }
  }

#pragma unroll
  for (int j = 0; j < 16; ++j) {
    int col = n0 + j * 16 + ln;
    int row = t * 64 + w * 16 + quad * 4;
    size_t base = ((size_t)b * 4096 + row) * 1024 + col;
#pragma unroll
    for (int r = 0; r < 4; ++r) out[base + (size_t)r * 1024] = acc[j][r];
  }
}

extern "C" void kernel_launch(void* const* d_in, const int* in_sizes, int n_in,
                              void* d_out, int out_size, void* d_ws, size_t ws_size,
                              hipStream_t stream) {
  const float* x  = (const float*)d_in[0];
  const float* Wq = (const float*)d_in[1];
  const float* bq = (const float*)d_in[2];
  const float* Wk = (const float*)d_in[3];
  const float* bk = (const float*)d_in[4];
  const float* Wv = (const float*)d_in[5];
  const float* bv = (const float*)d_in[6];
  float* out = (float*)d_out;

  _Float16* ws = (_Float16*)d_ws;
  _Float16* xh = ws;                    // 33554432
  _Float16* wt = ws + 33554432;         // 3145728
  _Float16* qh = ws + 36700160;         // 33554432
  _Float16* kh = ws + 70254592;         // 33554432
  _Float16* v8 = ws + 103809024;        // 33554432
  _Float16* ph = ws;                    // aliases xh (dead after GEMM1); 10485760

  k_cvt_x<<<16384, 256, 0, stream>>>(x, xh);
  k_cvt_w<<<dim3(16, 16, 3), 256, 0, stream>>>(Wq, Wk, Wv, wt);
  k_gemm_qkv<<<dim3(1536), 512, 0, stream>>>(xh, wt, bq, bk, bv, qh, kh, v8);
  k_scores<<<dim3(64, 8), 256, 0, stream>>>(qh, kh, ph);
  k_pv<<<dim3(4, 64, 8), 256, 0, stream>>>(ph, v8, out);
}

// Round 2
// 556.424 us; speedup vs baseline: 1.2114x; 1.0255x over previous
//
#include <hip/hip_runtime.h>
#include <hip/hip_fp16.h>
#include <cstdint>

// B=8, S=4096, D=1024, window +-128, out fp32.
// Pipeline: cvt x->fp16; cvt+transpose W->fp16; QKV MFMA GEMM (256x256 8-phase,
// fused N=3072); banded QK^T+softmax -> P fp16 (pre-swizzled in HBM); banded
// PV -> fp32 out.
//
// R4: k_scores/k_pv rewritten. Old versions staged then s_waitcnt(0) drained
// every iter (zero overlap, ~900cy HBM latency exposed 16x/10x per block).
// New: QT=128 tiles (halves K halo traffic), 512 thr / 8 waves, double-buffered
// LDS with counted-vmcnt 2-phase schedule; k_pv stages P once per block (was:
// re-staged every iter) and double-buffers V with depth-1 prefetch + vmcnt(8)
// (output stores stay in flight). P stored pre-XOR-swizzled so k_pv's linear
// global_load_lds staging + swizzled ds_read is conflict-free (both-sides rule).
//
// Workspace (halves): xh[33554432] | wt[3*1048576] | qh[33554432] |
// kh[33554432] | v8[33554432]  (P aliases xh, dead after GEMM; 25MB used)

#define DEV __device__ __forceinline__

typedef _Float16 f16x8 __attribute__((ext_vector_type(8)));
typedef _Float16 f16x4 __attribute__((ext_vector_type(4)));
typedef float    f32x4 __attribute__((ext_vector_type(4)));

DEV _Float16 f2h(float f) { return (_Float16)f; }

DEV void gl16(const void* g, void* l) {
  __builtin_amdgcn_global_load_lds(
      (const __attribute__((address_space(1))) void*)(uintptr_t)g,
      (__attribute__((address_space(3))) void*)(uintptr_t)l, 16, 0, 0);
}

#define MFMA16(a, b, c) __builtin_amdgcn_mfma_f32_16x16x32_f16((a), (b), (c), 0, 0, 0)

// ---------------- convert x (fp32 -> fp16), 8 elems/thread ----------------
__global__ __launch_bounds__(256) void k_cvt_x(const float* __restrict__ x,
                                               _Float16* __restrict__ xh) {
  size_t i = ((size_t)blockIdx.x * 256 + threadIdx.x) * 8;
  float4 f0 = *(const float4*)(x + i);
  float4 f1 = *(const float4*)(x + i + 4);
  f16x8 o;
  o[0] = f2h(f0.x); o[1] = f2h(f0.y); o[2] = f2h(f0.z); o[3] = f2h(f0.w);
  o[4] = f2h(f1.x); o[5] = f2h(f1.y); o[6] = f2h(f1.z); o[7] = f2h(f1.w);
  *(f16x8*)(xh + i) = o;
}

// ------------- transpose+convert W [k][n] fp32 -> Wt [n][k] fp16 -------------
__global__ __launch_bounds__(256) void k_cvt_w(const float* __restrict__ Wq,
                                               const float* __restrict__ Wk,
                                               const float* __restrict__ Wv,
                                               _Float16* __restrict__ wt) {
  __shared__ float tile[64][65];
  const int z = blockIdx.z;
  const int n0 = blockIdx.x * 64, k0 = blockIdx.y * 64;
  const float* W = (z == 0) ? Wq : (z == 1) ? Wk : Wv;
  const int tid = threadIdx.x;
  const int r0 = tid >> 4;           // 0..15
  const int c4 = (tid & 15) * 4;     // 0..60
#pragma unroll
  for (int rr = 0; rr < 4; ++rr) {
    int r = r0 + rr * 16;
    float4 v = *(const float4*)(W + (size_t)(k0 + r) * 1024 + n0 + c4);
    tile[r][c4 + 0] = v.x; tile[r][c4 + 1] = v.y;
    tile[r][c4 + 2] = v.z; tile[r][c4 + 3] = v.w;
  }
  __syncthreads();
  _Float16* out = wt + (size_t)z * 1048576;
#pragma unroll
  for (int rr = 0; rr < 4; ++rr) {
    int n = r0 + rr * 16;
    f16x4 o;
#pragma unroll
    for (int jj = 0; jj < 4; ++jj) o[jj] = f2h(tile[c4 + jj][n]);
    *(f16x4*)(out + (size_t)(n0 + n) * 1024 + k0 + c4) = o;
  }
}

// ---- QKV GEMM: [32768x1024] x Wt^T (N=3072 fused), 256x256 tile, 8-phase ----
__global__ __launch_bounds__(512, 2) void k_gemm_qkv(
    const _Float16* __restrict__ xh, const _Float16* __restrict__ wt,
    const float* __restrict__ bq, const float* __restrict__ bk,
    const float* __restrict__ bv, _Float16* __restrict__ qh,
    _Float16* __restrict__ kh, _Float16* __restrict__ v8) {
  // LDS: [buf 0/1][ A 256x64 | B 256x64 ] halves; 131072 bytes total.
  __shared__ _Float16 L[65536];

  // XCD-aware swizzle: 1536 blocks, 1536 % 8 == 0 -> simple bijective remap.
  const int bid = blockIdx.x;
  const int wg = (bid & 7) * 192 + (bid >> 3);
  const int mt = wg / 12, nt = wg % 12;   // 128 m-tiles x 12 n-tiles
  const int gm0 = mt * 256;
  const int gn0 = nt * 256;               // global n in [0,3072)

  const int tid = threadIdx.x;
  const int w = tid >> 6, l = tid & 63;   // 8 waves
  const int ln = l & 15, quad = l >> 4;
  const int wm = w >> 2, wn = w & 3;      // 2x4 wave grid, 128x64 out each
  const int lr = l >> 3;                  // 0..7
  const int kc = ((l & 7) ^ lr) * 8;      // pre-swizzled source k-column
  const int swz = ln & 7;                 // fragment-read octet xor

  // stage one 128x64 half-tile (2 x global_load_lds per thread)
  auto stageA = [&](int it, int h) {
    const _Float16* src =
        xh + (size_t)(gm0 + h * 128 + w * 8 + lr) * 1024 + it * 64 + kc;
    _Float16* dst = L + (it & 1) * 32768 + (h * 128 + w * 8) * 64;
    gl16(src, dst);
    gl16(src + 64 * 1024, dst + 64 * 64);
  };
  auto stageB = [&](int it, int h) {
    const _Float16* src =
        wt + (size_t)(gn0 + h * 128 + w * 8 + lr) * 1024 + it * 64 + kc;
    _Float16* dst = L + (it & 1) * 32768 + 16384 + (h * 128 + w * 8) * 64;
    gl16(src, dst);
    gl16(src + 64 * 1024, dst + 64 * 64);
  };

#define RD(base, r, ko) \
  (*(const f16x8*)((base) + (size_t)(r) * 64 + (((ko) ^ swz) * 8)))

  f32x4 acc[8][4] = {};
  f16x8 aA[2][4], bb0[2][2], bb1[2][2];

  // Prologue: tile0 fully + B halves of tile1; wait first 8 loads (tile0).
  stageA(0, 0); stageA(0, 1); stageB(0, 0); stageB(0, 1);
  stageB(1, 0); stageB(1, 1);
  asm volatile("s_waitcnt vmcnt(4)" ::: "memory");
  __builtin_amdgcn_s_barrier();

#pragma unroll 2
  for (int t = 0; t < 16; ++t) {
    const _Float16* Ab = L + (t & 1) * 32768;
    const _Float16* Bb = Ab + 16384;
    const int rA = wm * 128 + ln;
    const int rB = wn * 64 + ln;

    // ---------------- P1: A0+B0 reads | stage A0(t+1) | MFMA Q00 ----------------
#pragma unroll
    for (int i = 0; i < 4; ++i) {
      aA[0][i] = RD(Ab, rA + i * 16, quad);
      aA[1][i] = RD(Ab, rA + i * 16, quad + 4);
    }
#pragma unroll
    for (int j = 0; j < 2; ++j) {
      bb0[0][j] = RD(Bb, rB + j * 16, quad);
      bb0[1][j] = RD(Bb, rB + j * 16, quad + 4);
    }
    if (t + 1 < 16) stageA(t + 1, 0);
    __builtin_amdgcn_s_barrier();
    asm volatile("s_waitcnt lgkmcnt(0)" ::: "memory");
    __builtin_amdgcn_sched_barrier(0);
    __builtin_amdgcn_s_setprio(1);
#pragma unroll
    for (int s = 0; s < 2; ++s)
#pragma unroll
      for (int i = 0; i < 4; ++i)
#pragma unroll
        for (int j = 0; j < 2; ++j)
          acc[i][j] = MFMA16(aA[s][i], bb0[s][j], acc[i][j]);
    __builtin_amdgcn_s_setprio(0);
    __builtin_amdgcn_s_barrier();

    // ---------------- P2: B1 reads | stage A1(t+1) | MFMA Q01 ----------------
#pragma unroll
    for (int j = 0; j < 2; ++j) {
      bb1[0][j] = RD(Bb, rB + 32 + j * 16, quad);
      bb1[1][j] = RD(Bb, rB + 32 + j * 16, quad + 4);
    }
    if (t + 1 < 16) stageA(t + 1, 1);
    __builtin_amdgcn_s_barrier();
    asm volatile("s_waitcnt lgkmcnt(0)" ::: "memory");
    __builtin_amdgcn_sched_barrier(0);
    __builtin_amdgcn_s_setprio(1);
#pragma unroll
    for (int s = 0; s < 2; ++s)
#pragma unroll
      for (int i = 0; i < 4; ++i)
#pragma unroll
        for (int j = 0; j < 2; ++j)
          acc[i][2 + j] = MFMA16(aA[s][i], bb1[s][j], acc[i][2 + j]);
    __builtin_amdgcn_s_setprio(0);
    __builtin_amdgcn_s_barrier();

    // ---------------- P3: A1 reads | stage B0(t+2) | MFMA Q11 ----------------
#pragma unroll
    for (int i = 0; i < 4; ++i) {
      aA[0][i] = RD(Ab, rA + 64 + i * 16, quad);
      aA[1][i] = RD(Ab, rA + 64 + i * 16, quad + 4);
    }
    if (t + 2 < 16) stageB(t + 2, 0);
    __builtin_amdgcn_s_barrier();
    asm volatile("s_waitcnt lgkmcnt(0)" ::: "memory");
    __builtin_amdgcn_sched_barrier(0);
    __builtin_amdgcn_s_setprio(1);
#pragma unroll
    for (int s = 0; s < 2; ++s)
#pragma unroll
      for (int i = 0; i < 4; ++i)
#pragma unroll
        for (int j = 0; j < 2; ++j)
          acc[4 + i][2 + j] = MFMA16(aA[s][i], bb1[s][j], acc[4 + i][2 + j]);
    __builtin_amdgcn_s_setprio(0);
    __builtin_amdgcn_s_barrier();

    // ------------- P4: (regs only) | stage B1(t+2) | MFMA Q10 | vmcnt -------------
    if (t + 2 < 16) stageB(t + 2, 1);
    __builtin_amdgcn_s_setprio(1);
#pragma unroll
    for (int s = 0; s < 2; ++s)
#pragma unroll
      for (int i = 0; i < 4; ++i)
#pragma unroll
        for (int j = 0; j < 2; ++j)
          acc[4 + i][j] = MFMA16(aA[s][i], bb0[s][j], acc[4 + i][j]);
    __builtin_amdgcn_s_setprio(0);
    if (t + 2 < 16)
      asm volatile("s_waitcnt vmcnt(4)" ::: "memory");
    else
      asm volatile("s_waitcnt vmcnt(0)" ::: "memory");
    __builtin_amdgcn_s_barrier();
  }
#undef RD

  // Epilogue: z from fused-n (each 256-tile entirely within one z).
  const int z2 = gn0 >> 10;
  const int colz = (gn0 & 1023) + wn * 64;
  const int row0 = gm0 + wm * 128;
  if (z2 != 2) {
    const float* bias = z2 ? bk : bq;
    _Float16* outp = z2 ? kh : qh;
#pragma unroll
    for (int j = 0; j < 4; ++j) {
      float bb = bias[colz + j * 16 + ln];
#pragma unroll
      for (int i = 0; i < 8; ++i) {
        int row = row0 + i * 16 + quad * 4;
        size_t base = (size_t)row * 1024 + colz + j * 16 + ln;
#pragma unroll
        for (int r = 0; r < 4; ++r)
          outp[base + (size_t)r * 1024] = f2h(acc[i][j][r] + bb);
      }
    }
  } else {
    // V in 8-inner layout: v8[(row/8)*8192 + col*8 + row%8]
#pragma unroll
    for (int j = 0; j < 4; ++j) {
      float bb = bv[colz + j * 16 + ln];
#pragma unroll
      for (int i = 0; i < 8; ++i) {
        int rr = row0 + i * 16 + quad * 4;  // 4 consecutive rows
        int col = colz + j * 16 + ln;
        f16x4 o;
#pragma unroll
        for (int r = 0; r < 4; ++r) o[r] = f2h(acc[i][j][r] + bb);
        *(f16x4*)(v8 + (size_t)(rr >> 3) * 8192 + (size_t)col * 8 + (rr & 7)) = o;
      }
    }
  }
}

// -------- banded scores + softmax: 128-q tile, 512 thr, 2x4 wave grid --------
// P written to HBM pre-XOR-swizzled: pt[row*384 + ((oct^(row&7))<<3) + (col&7)]
__global__ __launch_bounds__(512) void k_scores(const _Float16* __restrict__ qh,
                                                const _Float16* __restrict__ kh,
                                                _Float16* __restrict__ ph) {
  __shared__ _Float16 lQ[2][128 * 64];   // 32 KiB
  __shared__ _Float16 lK[2][384 * 64];   // 96 KiB
  __shared__ float redM[4][128];
  __shared__ float redS[4][128];
  const int t = blockIdx.x, b = blockIdx.y;
  const int i0 = t * 128, k0 = i0 - 128;  // 384-key window
  const int tid = threadIdx.x, w = tid >> 6, l = tid & 63;
  const int ln = l & 15, quad = l >> 4;
  const int wm2 = w >> 2, wn4 = w & 3;    // wave = 64 q x 96 k
  const _Float16* qrow = qh + (size_t)b * 4096 * 1024;
  const _Float16* krow = kh + (size_t)b * 4096 * 1024;
  const int kc = ((l & 7) ^ (l >> 3)) * 8;
  const int swz = ln & 7;

  auto stage = [&](int it) {
    int buf = it & 1;
#pragma unroll
    for (int c = 0; c < 2; ++c) {
      int cid = w * 2 + c;
      int rl = cid * 8 + (l >> 3);
      gl16(qrow + (size_t)(i0 + rl) * 1024 + it * 64 + kc, &lQ[buf][cid * 512]);
    }
#pragma unroll
    for (int c = 0; c < 6; ++c) {
      int cid = w * 6 + c;
      int rl = cid * 8 + (l >> 3);
      int gr = min(max(k0 + rl, 0), 4095);  // clamped rows masked below
      gl16(krow + (size_t)gr * 1024 + it * 64 + kc, &lK[buf][cid * 512]);
    }
  };

  f32x4 s[4][6] = {};

  stage(0);
  asm volatile("s_waitcnt vmcnt(0)" ::: "memory");
  __builtin_amdgcn_s_barrier();

  for (int it = 0; it < 16; ++it) {
    int buf = it & 1;
    if (it + 1 < 16) stage(it + 1);
    f16x8 af[2][4], bf[2][6];
#pragma unroll
    for (int i = 0; i < 4; ++i) {
      int r = wm2 * 64 + i * 16 + ln;
      af[0][i] = *(const f16x8*)(&lQ[buf][r * 64 + ((quad ^ swz) * 8)]);
      af[1][i] = *(const f16x8*)(&lQ[buf][r * 64 + (((quad + 4) ^ swz) * 8)]);
    }
#pragma unroll
    for (int j = 0; j < 6; ++j) {
      int r = wn4 * 96 + j * 16 + ln;
      bf[0][j] = *(const f16x8*)(&lK[buf][r * 64 + ((quad ^ swz) * 8)]);
      bf[1][j] = *(const f16x8*)(&lK[buf][r * 64 + (((quad + 4) ^ swz) * 8)]);
    }
    asm volatile("s_waitcnt lgkmcnt(0)" ::: "memory");
    __builtin_amdgcn_sched_barrier(0);
    __builtin_amdgcn_s_setprio(1);
#pragma unroll
    for (int ss = 0; ss < 2; ++ss)
#pragma unroll
      for (int i = 0; i < 4; ++i)
#pragma unroll
        for (int j = 0; j < 6; ++j)
          s[i][j] = MFMA16(af[ss][i], bf[ss][j], s[i][j]);
    __builtin_amdgcn_s_setprio(0);
    asm volatile("s_waitcnt vmcnt(0)" ::: "memory");
    __builtin_amdgcn_s_barrier();
  }

  // mask + scale; per-lane row maxima (C layout: col=ln key, row=quad*4+r)
  const float scale = 0.03125f;  // 1/sqrt(1024)
  float mrow[4][4];
#pragma unroll
  for (int i = 0; i < 4; ++i)
#pragma unroll
    for (int r = 0; r < 4; ++r) mrow[i][r] = -1e30f;
#pragma unroll
  for (int j = 0; j < 6; ++j) {
    int jc = k0 + wn4 * 96 + j * 16 + ln;
    bool cval = (jc >= 0) && (jc < 4096);
#pragma unroll
    for (int i = 0; i < 4; ++i)
#pragma unroll
      for (int r = 0; r < 4; ++r) {
        int iq = i0 + wm2 * 64 + i * 16 + quad * 4 + r;
        int rel = jc - iq;
        bool val = cval && (rel >= -128) && (rel <= 128);
        float sc = val ? s[i][j][r] * scale : -1e30f;
        s[i][j][r] = sc;
        mrow[i][r] = fmaxf(mrow[i][r], sc);
      }
  }
  // reduce over 16 key-lanes within quad
#pragma unroll
  for (int i = 0; i < 4; ++i)
#pragma unroll
    for (int r = 0; r < 4; ++r)
#pragma unroll
      for (int m = 1; m < 16; m <<= 1)
        mrow[i][r] = fmaxf(mrow[i][r], __shfl_xor(mrow[i][r], m));
  if (ln == 0) {
#pragma unroll
    for (int i = 0; i < 4; ++i)
#pragma unroll
      for (int r = 0; r < 4; ++r)
        redM[wn4][wm2 * 64 + i * 16 + quad * 4 + r] = mrow[i][r];
  }
  __syncthreads();
  float mf[4][4];
#pragma unroll
  for (int i = 0; i < 4; ++i)
#pragma unroll
    for (int r = 0; r < 4; ++r) {
      int row = wm2 * 64 + i * 16 + quad * 4 + r;
      mf[i][r] = fmaxf(fmaxf(redM[0][row], redM[1][row]),
                       fmaxf(redM[2][row], redM[3][row]));
    }
  float srow[4][4] = {};
#pragma unroll
  for (int j = 0; j < 6; ++j)
#pragma unroll
    for (int i = 0; i < 4; ++i)
#pragma unroll
      for (int r = 0; r < 4; ++r) {
        float e = __builtin_exp2f((s[i][j][r] - mf[i][r]) * 1.44269504f);
        s[i][j][r] = e;
        srow[i][r] += e;
      }
#pragma unroll
  for (int i = 0; i < 4; ++i)
#pragma unroll
    for (int r = 0; r < 4; ++r)
#pragma unroll
      for (int m = 1; m < 16; m <<= 1) srow[i][r] += __shfl_xor(srow[i][r], m);
  if (ln == 0) {
#pragma unroll
    for (int i = 0; i < 4; ++i)
#pragma unroll
      for (int r = 0; r < 4; ++r)
        redS[wn4][wm2 * 64 + i * 16 + quad * 4 + r] = srow[i][r];
  }
  __syncthreads();
  float inv[4][4];
#pragma unroll
  for (int i = 0; i < 4; ++i)
#pragma unroll
    for (int r = 0; r < 4; ++r) {
      int row = wm2 * 64 + i * 16 + quad * 4 + r;
      inv[i][r] = 1.0f / (redS[0][row] + redS[1][row] + redS[2][row] + redS[3][row]);
    }
  // write P pre-swizzled (octet ^ row&7) so k_pv can gl16-stage linearly
  _Float16* pt = ph + (size_t)(b * 32 + t) * 128 * 384;
#pragma unroll
  for (int j = 0; j < 6; ++j) {
    int col = wn4 * 96 + j * 16 + ln;
    int oct = col >> 3, e = col & 7;
#pragma unroll
    for (int i = 0; i < 4; ++i)
#pragma unroll
      for (int r = 0; r < 4; ++r) {
        int row = wm2 * 64 + i * 16 + quad * 4 + r;
        pt[row * 384 + ((oct ^ (row & 7)) << 3) + e] = f2h(s[i][j][r] * inv[i][r]);
      }
  }
}

// ------- PV: out[128 x 1024] = P[128 x 384] * V[384 x 1024], P LDS-resident -------
__global__ __launch_bounds__(512) void k_pv(const _Float16* __restrict__ ph,
                                            const _Float16* __restrict__ v8,
                                            float* __restrict__ out) {
  __shared__ _Float16 lP[128 * 384];       // 96 KiB, linear copy of pre-swizzled P
  __shared__ _Float16 lV[2][48 * 32 * 8];  // 2 x 24 KiB: [k-octet][n][8]
  const int t = blockIdx.x, b = blockIdx.y;
  const int tid = threadIdx.x, w = tid >> 6, l = tid & 63;
  const int ln = l & 15, quad = l >> 4;
  const int wq = w >> 1, wn2 = w & 1;      // wave = 32 q x 16 n per chunk
  const _Float16* pt = ph + (size_t)(b * 32 + t) * 128 * 384;
  const _Float16* vb = v8 + (size_t)b * 4194304;
  const int g0 = (t * 128 - 128) >> 3;     // first key octet (may be negative)

  auto stageV = [&](int c) {
    int buf = c & 1;
    int n0 = c * 32;
#pragma unroll
    for (int cc = 0; cc < 3; ++cc) {
      int ob = w * 6 + cc * 2;             // octet base, uniform in wave
      int oct = ob + (l >> 5);             // lanes 0-31 -> ob, 32-63 -> ob+1
      int g = min(max(g0 + oct, 0), 511);  // clamped keys have P==0
      gl16(vb + (size_t)g * 8192 + (size_t)(n0 + (l & 31)) * 8,
           &lV[buf][ob * 256]);
    }
  };

  // stage P once (12 gl16/thread) + V chunk 0; V1 issued after wait point
  #pragma unroll
  for (int c = 0; c < 12; ++c)
    gl16(pt + ((size_t)(c * 512 + w * 64 + l)) * 8, &lP[(c * 512 + w * 64) * 8]);
  stageV(0);
  stageV(1);
  asm volatile("s_waitcnt vmcnt(3)" ::: "memory");  // P + V0 done; V1 in flight
  __builtin_amdgcn_s_barrier();

  for (int c = 0; c < 32; ++c) {
    int buf = c & 1;
    if (c + 1 < 32) stageV(c + 1);
    f32x4 acc[2] = {};
#pragma unroll
    for (int ks = 0; ks < 12; ++ks) {
      int o = ks * 4 + quad;
      int rA0 = wq * 32 + ln;
      int rA1 = rA0 + 16;
      f16x8 a0 = *(const f16x8*)(&lP[rA0 * 384 + ((o ^ (rA0 & 7)) << 3)]);
      f16x8 a1 = *(const f16x8*)(&lP[rA1 * 384 + ((o ^ (rA1 & 7)) << 3)]);
      f16x8 bv = *(const f16x8*)(&lV[buf][(o * 32 + wn2 * 16 + ln) * 8]);
      acc[0] = MFMA16(a0, bv, acc[0]);
      acc[1] = MFMA16(a1, bv, acc[1]);
    }
    // store this chunk's 128x32 slice (stores stay in flight across vmcnt(8))
    int col = c * 32 + wn2 * 16 + ln;
#pragma unroll
    for (int i = 0; i < 2; ++i) {
      int row = t * 128 + wq * 32 + i * 16 + quad * 4;
      size_t base = ((size_t)b * 4096 + row) * 1024 + col;
#pragma unroll
      for (int r = 0; r < 4; ++r) out[base + (size_t)r * 1024] = acc[i][r];
    }
    if (c + 1 < 32) {
      // outstanding: 3 V(c+1) loads (oldest) + 8 stores -> wait loads only
      asm volatile("s_waitcnt vmcnt(8)" ::: "memory");
      __builtin_amdgcn_s_barrier();
    }
  }
}

extern "C" void kernel_launch(void* const* d_in, const int* in_sizes, int n_in,
                              void* d_out, int out_size, void* d_ws, size_t ws_size,
                              hipStream_t stream) {
  const float* x  = (const float*)d_in[0];
  const float* Wq = (const float*)d_in[1];
  const float* bq = (const float*)d_in[2];
  const float* Wk = (const float*)d_in[3];
  const float* bk = (const float*)d_in[4];
  const float* Wv = (const float*)d_in[5];
  const float* bv = (const float*)d_in[6];
  float* out = (float*)d_out;

  _Float16* ws = (_Float16*)d_ws;
  _Float16* xh = ws;                    // 33554432
  _Float16* wt = ws + 33554432;         // 3145728
  _Float16* qh = ws + 36700160;         // 33554432
  _Float16* kh = ws + 70254592;         // 33554432
  _Float16* v8 = ws + 103809024;        // 33554432
  _Float16* ph = ws;                    // aliases xh (dead after GEMM); 12.6M halves

  k_cvt_x<<<16384, 256, 0, stream>>>(x, xh);
  k_cvt_w<<<dim3(16, 16, 3), 256, 0, stream>>>(Wq, Wk, Wv, wt);
  k_gemm_qkv<<<dim3(1536), 512, 0, stream>>>(xh, wt, bq, bk, bv, qh, kh, v8);
  k_scores<<<dim3(32, 8), 512, 0, stream>>>(qh, kh, ph);
  k_pv<<<dim3(32, 8), 512, 0, stream>>>(ph, v8, out);
}

// Round 3
// 524.000 us; speedup vs baseline: 1.2864x; 1.0619x over previous
//
#include <hip/hip_runtime.h>
#include <hip/hip_fp16.h>
#include <cstdint>

// B=8, S=4096, D=1024, window +-128, out fp32.
// Pipeline: cvt x->fp16; cvt+transpose W->fp16; QKV MFMA GEMM (256x256 8-phase,
// fused N=3072); FUSED banded attention (QK^T + softmax + PV) with P in LDS.
//
// R5: k_scores+k_pv fused into k_attn. P never touches HBM (was a 50 MB
// round-trip + 12 gl16/thread re-staging in k_pv). LDS is phase-unioned:
//   phase A (QK^T): lQ 2x8192h @0 | lK 2x24576h @16384 | red 2048h @65536
//   phase B (PV):   lP 49152h @0  | lV 2x12288h @49152
// peak 73728 halves = 147456 B (1 block/CU, 8 waves). Softmax writes P
// directly into LDS pre-XOR-swizzled (oct ^ row&7) matching PV's fragment
// reads (both-sides-or-neither). Also fixes k_pv's duplicate stageV(1).
//
// Workspace (halves): xh[33554432] | wt[3*1048576] | qh[33554432] |
// kh[33554432] | v8[33554432]

#define DEV __device__ __forceinline__

typedef _Float16 f16x8 __attribute__((ext_vector_type(8)));
typedef _Float16 f16x4 __attribute__((ext_vector_type(4)));
typedef float    f32x4 __attribute__((ext_vector_type(4)));

DEV _Float16 f2h(float f) { return (_Float16)f; }

DEV void gl16(const void* g, void* l) {
  __builtin_amdgcn_global_load_lds(
      (const __attribute__((address_space(1))) void*)(uintptr_t)g,
      (__attribute__((address_space(3))) void*)(uintptr_t)l, 16, 0, 0);
}

#define MFMA16(a, b, c) __builtin_amdgcn_mfma_f32_16x16x32_f16((a), (b), (c), 0, 0, 0)

// ---------------- convert x (fp32 -> fp16), 8 elems/thread ----------------
__global__ __launch_bounds__(256) void k_cvt_x(const float* __restrict__ x,
                                               _Float16* __restrict__ xh) {
  size_t i = ((size_t)blockIdx.x * 256 + threadIdx.x) * 8;
  float4 f0 = *(const float4*)(x + i);
  float4 f1 = *(const float4*)(x + i + 4);
  f16x8 o;
  o[0] = f2h(f0.x); o[1] = f2h(f0.y); o[2] = f2h(f0.z); o[3] = f2h(f0.w);
  o[4] = f2h(f1.x); o[5] = f2h(f1.y); o[6] = f2h(f1.z); o[7] = f2h(f1.w);
  *(f16x8*)(xh + i) = o;
}

// ------------- transpose+convert W [k][n] fp32 -> Wt [n][k] fp16 -------------
__global__ __launch_bounds__(256) void k_cvt_w(const float* __restrict__ Wq,
                                               const float* __restrict__ Wk,
                                               const float* __restrict__ Wv,
                                               _Float16* __restrict__ wt) {
  __shared__ float tile[64][65];
  const int z = blockIdx.z;
  const int n0 = blockIdx.x * 64, k0 = blockIdx.y * 64;
  const float* W = (z == 0) ? Wq : (z == 1) ? Wk : Wv;
  const int tid = threadIdx.x;
  const int r0 = tid >> 4;           // 0..15
  const int c4 = (tid & 15) * 4;     // 0..60
#pragma unroll
  for (int rr = 0; rr < 4; ++rr) {
    int r = r0 + rr * 16;
    float4 v = *(const float4*)(W + (size_t)(k0 + r) * 1024 + n0 + c4);
    tile[r][c4 + 0] = v.x; tile[r][c4 + 1] = v.y;
    tile[r][c4 + 2] = v.z; tile[r][c4 + 3] = v.w;
  }
  __syncthreads();
  _Float16* out = wt + (size_t)z * 1048576;
#pragma unroll
  for (int rr = 0; rr < 4; ++rr) {
    int n = r0 + rr * 16;
    f16x4 o;
#pragma unroll
    for (int jj = 0; jj < 4; ++jj) o[jj] = f2h(tile[c4 + jj][n]);
    *(f16x4*)(out + (size_t)(n0 + n) * 1024 + k0 + c4) = o;
  }
}

// ---- QKV GEMM: [32768x1024] x Wt^T (N=3072 fused), 256x256 tile, 8-phase ----
__global__ __launch_bounds__(512, 2) void k_gemm_qkv(
    const _Float16* __restrict__ xh, const _Float16* __restrict__ wt,
    const float* __restrict__ bq, const float* __restrict__ bk,
    const float* __restrict__ bv, _Float16* __restrict__ qh,
    _Float16* __restrict__ kh, _Float16* __restrict__ v8) {
  // LDS: [buf 0/1][ A 256x64 | B 256x64 ] halves; 131072 bytes total.
  __shared__ _Float16 L[65536];

  // XCD-aware swizzle: 1536 blocks, 1536 % 8 == 0 -> simple bijective remap.
  const int bid = blockIdx.x;
  const int wg = (bid & 7) * 192 + (bid >> 3);
  const int mt = wg / 12, nt = wg % 12;   // 128 m-tiles x 12 n-tiles
  const int gm0 = mt * 256;
  const int gn0 = nt * 256;               // global n in [0,3072)

  const int tid = threadIdx.x;
  const int w = tid >> 6, l = tid & 63;   // 8 waves
  const int ln = l & 15, quad = l >> 4;
  const int wm = w >> 2, wn = w & 3;      // 2x4 wave grid, 128x64 out each
  const int lr = l >> 3;                  // 0..7
  const int kc = ((l & 7) ^ lr) * 8;      // pre-swizzled source k-column
  const int swz = ln & 7;                 // fragment-read octet xor

  // stage one 128x64 half-tile (2 x global_load_lds per thread)
  auto stageA = [&](int it, int h) {
    const _Float16* src =
        xh + (size_t)(gm0 + h * 128 + w * 8 + lr) * 1024 + it * 64 + kc;
    _Float16* dst = L + (it & 1) * 32768 + (h * 128 + w * 8) * 64;
    gl16(src, dst);
    gl16(src + 64 * 1024, dst + 64 * 64);
  };
  auto stageB = [&](int it, int h) {
    const _Float16* src =
        wt + (size_t)(gn0 + h * 128 + w * 8 + lr) * 1024 + it * 64 + kc;
    _Float16* dst = L + (it & 1) * 32768 + 16384 + (h * 128 + w * 8) * 64;
    gl16(src, dst);
    gl16(src + 64 * 1024, dst + 64 * 64);
  };

#define RD(base, r, ko) \
  (*(const f16x8*)((base) + (size_t)(r) * 64 + (((ko) ^ swz) * 8)))

  f32x4 acc[8][4] = {};
  f16x8 aA[2][4], bb0[2][2], bb1[2][2];

  // Prologue: tile0 fully + B halves of tile1; wait first 8 loads (tile0).
  stageA(0, 0); stageA(0, 1); stageB(0, 0); stageB(0, 1);
  stageB(1, 0); stageB(1, 1);
  asm volatile("s_waitcnt vmcnt(4)" ::: "memory");
  __builtin_amdgcn_s_barrier();

#pragma unroll 2
  for (int t = 0; t < 16; ++t) {
    const _Float16* Ab = L + (t & 1) * 32768;
    const _Float16* Bb = Ab + 16384;
    const int rA = wm * 128 + ln;
    const int rB = wn * 64 + ln;

    // ---------------- P1: A0+B0 reads | stage A0(t+1) | MFMA Q00 ----------------
#pragma unroll
    for (int i = 0; i < 4; ++i) {
      aA[0][i] = RD(Ab, rA + i * 16, quad);
      aA[1][i] = RD(Ab, rA + i * 16, quad + 4);
    }
#pragma unroll
    for (int j = 0; j < 2; ++j) {
      bb0[0][j] = RD(Bb, rB + j * 16, quad);
      bb0[1][j] = RD(Bb, rB + j * 16, quad + 4);
    }
    if (t + 1 < 16) stageA(t + 1, 0);
    __builtin_amdgcn_s_barrier();
    asm volatile("s_waitcnt lgkmcnt(0)" ::: "memory");
    __builtin_amdgcn_sched_barrier(0);
    __builtin_amdgcn_s_setprio(1);
#pragma unroll
    for (int s = 0; s < 2; ++s)
#pragma unroll
      for (int i = 0; i < 4; ++i)
#pragma unroll
        for (int j = 0; j < 2; ++j)
          acc[i][j] = MFMA16(aA[s][i], bb0[s][j], acc[i][j]);
    __builtin_amdgcn_s_setprio(0);
    __builtin_amdgcn_s_barrier();

    // ---------------- P2: B1 reads | stage A1(t+1) | MFMA Q01 ----------------
#pragma unroll
    for (int j = 0; j < 2; ++j) {
      bb1[0][j] = RD(Bb, rB + 32 + j * 16, quad);
      bb1[1][j] = RD(Bb, rB + 32 + j * 16, quad + 4);
    }
    if (t + 1 < 16) stageA(t + 1, 1);
    __builtin_amdgcn_s_barrier();
    asm volatile("s_waitcnt lgkmcnt(0)" ::: "memory");
    __builtin_amdgcn_sched_barrier(0);
    __builtin_amdgcn_s_setprio(1);
#pragma unroll
    for (int s = 0; s < 2; ++s)
#pragma unroll
      for (int i = 0; i < 4; ++i)
#pragma unroll
        for (int j = 0; j < 2; ++j)
          acc[i][2 + j] = MFMA16(aA[s][i], bb1[s][j], acc[i][2 + j]);
    __builtin_amdgcn_s_setprio(0);
    __builtin_amdgcn_s_barrier();

    // ---------------- P3: A1 reads | stage B0(t+2) | MFMA Q11 ----------------
#pragma unroll
    for (int i = 0; i < 4; ++i) {
      aA[0][i] = RD(Ab, rA + 64 + i * 16, quad);
      aA[1][i] = RD(Ab, rA + 64 + i * 16, quad + 4);
    }
    if (t + 2 < 16) stageB(t + 2, 0);
    __builtin_amdgcn_s_barrier();
    asm volatile("s_waitcnt lgkmcnt(0)" ::: "memory");
    __builtin_amdgcn_sched_barrier(0);
    __builtin_amdgcn_s_setprio(1);
#pragma unroll
    for (int s = 0; s < 2; ++s)
#pragma unroll
      for (int i = 0; i < 4; ++i)
#pragma unroll
        for (int j = 0; j < 2; ++j)
          acc[4 + i][2 + j] = MFMA16(aA[s][i], bb1[s][j], acc[4 + i][2 + j]);
    __builtin_amdgcn_s_setprio(0);
    __builtin_amdgcn_s_barrier();

    // ------------- P4: (regs only) | stage B1(t+2) | MFMA Q10 | vmcnt -------------
    if (t + 2 < 16) stageB(t + 2, 1);
    __builtin_amdgcn_s_setprio(1);
#pragma unroll
    for (int s = 0; s < 2; ++s)
#pragma unroll
      for (int i = 0; i < 4; ++i)
#pragma unroll
        for (int j = 0; j < 2; ++j)
          acc[4 + i][j] = MFMA16(aA[s][i], bb0[s][j], acc[4 + i][j]);
    __builtin_amdgcn_s_setprio(0);
    if (t + 2 < 16)
      asm volatile("s_waitcnt vmcnt(4)" ::: "memory");
    else
      asm volatile("s_waitcnt vmcnt(0)" ::: "memory");
    __builtin_amdgcn_s_barrier();
  }
#undef RD

  // Epilogue: z from fused-n (each 256-tile entirely within one z).
  const int z2 = gn0 >> 10;
  const int colz = (gn0 & 1023) + wn * 64;
  const int row0 = gm0 + wm * 128;
  if (z2 != 2) {
    const float* bias = z2 ? bk : bq;
    _Float16* outp = z2 ? kh : qh;
#pragma unroll
    for (int j = 0; j < 4; ++j) {
      float bb = bias[colz + j * 16 + ln];
#pragma unroll
      for (int i = 0; i < 8; ++i) {
        int row = row0 + i * 16 + quad * 4;
        size_t base = (size_t)row * 1024 + colz + j * 16 + ln;
#pragma unroll
        for (int r = 0; r < 4; ++r)
          outp[base + (size_t)r * 1024] = f2h(acc[i][j][r] + bb);
      }
    }
  } else {
    // V in 8-inner layout: v8[(row/8)*8192 + col*8 + row%8]
#pragma unroll
    for (int j = 0; j < 4; ++j) {
      float bb = bv[colz + j * 16 + ln];
#pragma unroll
      for (int i = 0; i < 8; ++i) {
        int rr = row0 + i * 16 + quad * 4;  // 4 consecutive rows
        int col = colz + j * 16 + ln;
        f16x4 o;
#pragma unroll
        for (int r = 0; r < 4; ++r) o[r] = f2h(acc[i][j][r] + bb);
        *(f16x4*)(v8 + (size_t)(rr >> 3) * 8192 + (size_t)col * 8 + (rr & 7)) = o;
      }
    }
  }
}

// ------ fused banded attention: QK^T + softmax (P in LDS) + PV, 128-q tile ------
__global__ __launch_bounds__(512, 2) void k_attn(const _Float16* __restrict__ qh,
                                                 const _Float16* __restrict__ kh,
                                                 const _Float16* __restrict__ v8,
                                                 float* __restrict__ out) {
  // Phase-unioned LDS (halves):
  //  A: lQ 2x8192 @0 | lK 2x24576 @16384 | red(float) 1024 @65536
  //  B: lP 49152 @0  | lV 2x12288 @49152
  __shared__ _Float16 smem[73728];  // 147456 B
  const int t = blockIdx.x, b = blockIdx.y;
  const int i0 = t * 128, k0 = i0 - 128;  // 384-key window
  const int tid = threadIdx.x, w = tid >> 6, l = tid & 63;
  const int ln = l & 15, quad = l >> 4;
  const int wm2 = w >> 2, wn4 = w & 3;    // QK wave = 64 q x 96 k
  const _Float16* qrow = qh + (size_t)b * 4096 * 1024;
  const _Float16* krow = kh + (size_t)b * 4096 * 1024;
  const _Float16* vb = v8 + (size_t)b * 4194304;
  const int kc = ((l & 7) ^ (l >> 3)) * 8;
  const int swz = ln & 7;

  // ---------------- phase A: QK^T ----------------
  auto stage = [&](int it) {
    int buf = it & 1;
#pragma unroll
    for (int c = 0; c < 2; ++c) {
      int cid = w * 2 + c;
      int rl = cid * 8 + (l >> 3);
      gl16(qrow + (size_t)(i0 + rl) * 1024 + it * 64 + kc,
           &smem[buf * 8192 + cid * 512]);
    }
#pragma unroll
    for (int c = 0; c < 6; ++c) {
      int cid = w * 6 + c;
      int rl = cid * 8 + (l >> 3);
      int gr = min(max(k0 + rl, 0), 4095);  // clamped rows masked below
      gl16(krow + (size_t)gr * 1024 + it * 64 + kc,
           &smem[16384 + buf * 24576 + cid * 512]);
    }
  };

  f32x4 s[4][6] = {};

  stage(0);
  asm volatile("s_waitcnt vmcnt(0)" ::: "memory");
  __builtin_amdgcn_s_barrier();

  for (int it = 0; it < 16; ++it) {
    int buf = it & 1;
    if (it + 1 < 16) stage(it + 1);
    f16x8 af[2][4], bf[2][6];
#pragma unroll
    for (int i = 0; i < 4; ++i) {
      int r = wm2 * 64 + i * 16 + ln;
      af[0][i] = *(const f16x8*)(&smem[buf * 8192 + r * 64 + ((quad ^ swz) * 8)]);
      af[1][i] = *(const f16x8*)(&smem[buf * 8192 + r * 64 + (((quad + 4) ^ swz) * 8)]);
    }
#pragma unroll
    for (int j = 0; j < 6; ++j) {
      int r = wn4 * 96 + j * 16 + ln;
      bf[0][j] = *(const f16x8*)(&smem[16384 + buf * 24576 + r * 64 + ((quad ^ swz) * 8)]);
      bf[1][j] = *(const f16x8*)(&smem[16384 + buf * 24576 + r * 64 + (((quad + 4) ^ swz) * 8)]);
    }
    asm volatile("s_waitcnt lgkmcnt(0)" ::: "memory");
    __builtin_amdgcn_sched_barrier(0);
    __builtin_amdgcn_s_setprio(1);
#pragma unroll
    for (int ss = 0; ss < 2; ++ss)
#pragma unroll
      for (int i = 0; i < 4; ++i)
#pragma unroll
        for (int j = 0; j < 6; ++j)
          s[i][j] = MFMA16(af[ss][i], bf[ss][j], s[i][j]);
    __builtin_amdgcn_s_setprio(0);
    asm volatile("s_waitcnt vmcnt(0)" ::: "memory");
    __builtin_amdgcn_s_barrier();
  }

  // ---------------- softmax (C layout: col=ln key, row=quad*4+r) ----------------
  float* redM = (float*)(&smem[65536]);
  float* redS = redM + 512;
  const float scale = 0.03125f;  // 1/sqrt(1024)
  float mrow[4][4];
#pragma unroll
  for (int i = 0; i < 4; ++i)
#pragma unroll
    for (int r = 0; r < 4; ++r) mrow[i][r] = -1e30f;
#pragma unroll
  for (int j = 0; j < 6; ++j) {
    int jc = k0 + wn4 * 96 + j * 16 + ln;
    bool cval = (jc >= 0) && (jc < 4096);
#pragma unroll
    for (int i = 0; i < 4; ++i)
#pragma unroll
      for (int r = 0; r < 4; ++r) {
        int iq = i0 + wm2 * 64 + i * 16 + quad * 4 + r;
        int rel = jc - iq;
        bool val = cval && (rel >= -128) && (rel <= 128);
        float sc = val ? s[i][j][r] * scale : -1e30f;
        s[i][j][r] = sc;
        mrow[i][r] = fmaxf(mrow[i][r], sc);
      }
  }
#pragma unroll
  for (int i = 0; i < 4; ++i)
#pragma unroll
    for (int r = 0; r < 4; ++r)
#pragma unroll
      for (int m = 1; m < 16; m <<= 1)
        mrow[i][r] = fmaxf(mrow[i][r], __shfl_xor(mrow[i][r], m));
  if (ln == 0) {
#pragma unroll
    for (int i = 0; i < 4; ++i)
#pragma unroll
      for (int r = 0; r < 4; ++r)
        redM[wn4 * 128 + wm2 * 64 + i * 16 + quad * 4 + r] = mrow[i][r];
  }
  __syncthreads();
  float mf[4][4];
#pragma unroll
  for (int i = 0; i < 4; ++i)
#pragma unroll
    for (int r = 0; r < 4; ++r) {
      int row = wm2 * 64 + i * 16 + quad * 4 + r;
      mf[i][r] = fmaxf(fmaxf(redM[row], redM[128 + row]),
                       fmaxf(redM[256 + row], redM[384 + row]));
    }
  float srow[4][4] = {};
#pragma unroll
  for (int j = 0; j < 6; ++j)
#pragma unroll
    for (int i = 0; i < 4; ++i)
#pragma unroll
      for (int r = 0; r < 4; ++r) {
        float e = __builtin_exp2f((s[i][j][r] - mf[i][r]) * 1.44269504f);
        s[i][j][r] = e;
        srow[i][r] += e;
      }
#pragma unroll
  for (int i = 0; i < 4; ++i)
#pragma unroll
    for (int r = 0; r < 4; ++r)
#pragma unroll
      for (int m = 1; m < 16; m <<= 1) srow[i][r] += __shfl_xor(srow[i][r], m);
  if (ln == 0) {
#pragma unroll
    for (int i = 0; i < 4; ++i)
#pragma unroll
      for (int r = 0; r < 4; ++r)
        redS[wn4 * 128 + wm2 * 64 + i * 16 + quad * 4 + r] = srow[i][r];
  }
  __syncthreads();
  float inv[4][4];
#pragma unroll
  for (int i = 0; i < 4; ++i)
#pragma unroll
    for (int r = 0; r < 4; ++r) {
      int row = wm2 * 64 + i * 16 + quad * 4 + r;
      inv[i][r] = 1.0f / (redS[row] + redS[128 + row] + redS[256 + row] + redS[384 + row]);
    }
  // write P into LDS pre-swizzled (octet ^ row&7); overwrites dead lQ/lK
#pragma unroll
  for (int j = 0; j < 6; ++j) {
    int col = wn4 * 96 + j * 16 + ln;
    int oct = col >> 3, e = col & 7;
#pragma unroll
    for (int i = 0; i < 4; ++i)
#pragma unroll
      for (int r = 0; r < 4; ++r) {
        int row = wm2 * 64 + i * 16 + quad * 4 + r;
        smem[row * 384 + ((oct ^ (row & 7)) << 3) + e] = f2h(s[i][j][r] * inv[i][r]);
      }
  }
  __syncthreads();  // P visible; red reads done -> lV region reusable

  // ---------------- phase B: PV (P LDS-resident) ----------------
  const int wq = w >> 1, wn2 = w & 1;      // wave = 32 q x 16 n per chunk
  const int g0 = (t * 128 - 128) >> 3;     // first key octet (may be negative)
  _Float16* lV = &smem[49152];             // [2][48*32*8]

  auto stageV = [&](int c) {
    int buf = c & 1;
    int n0 = c * 32;
#pragma unroll
    for (int cc = 0; cc < 3; ++cc) {
      int ob = w * 6 + cc * 2;             // octet base, uniform in wave
      int oct = ob + (l >> 5);             // lanes 0-31 -> ob, 32-63 -> ob+1
      int g = min(max(g0 + oct, 0), 511);  // clamped keys have P==0
      gl16(vb + (size_t)g * 8192 + (size_t)(n0 + (l & 31)) * 8,
           &lV[buf * 12288 + ob * 256]);
    }
  };

  stageV(0);
  stageV(1);
  asm volatile("s_waitcnt vmcnt(3)" ::: "memory");  // V0 done; V1 in flight
  __builtin_amdgcn_s_barrier();

  for (int c = 0; c < 32; ++c) {
    int buf = c & 1;
    if (c >= 1 && c + 1 < 32) stageV(c + 1);  // V1 already staged in prologue
    f32x4 acc[2] = {};
#pragma unroll
    for (int ks = 0; ks < 12; ++ks) {
      int o = ks * 4 + quad;
      int rA0 = wq * 32 + ln;
      int rA1 = rA0 + 16;
      f16x8 a0 = *(const f16x8*)(&smem[rA0 * 384 + ((o ^ (rA0 & 7)) << 3)]);
      f16x8 a1 = *(const f16x8*)(&smem[rA1 * 384 + ((o ^ (rA1 & 7)) << 3)]);
      f16x8 bv = *(const f16x8*)(&lV[buf * 12288 + (o * 32 + wn2 * 16 + ln) * 8]);
      acc[0] = MFMA16(a0, bv, acc[0]);
      acc[1] = MFMA16(a1, bv, acc[1]);
    }
    // store this chunk's 128x32 slice (stores stay in flight across vmcnt(8))
    int col = c * 32 + wn2 * 16 + ln;
#pragma unroll
    for (int i = 0; i < 2; ++i) {
      int row = t * 128 + wq * 32 + i * 16 + quad * 4;
      size_t base = ((size_t)b * 4096 + row) * 1024 + col;
#pragma unroll
      for (int r = 0; r < 4; ++r) out[base + (size_t)r * 1024] = acc[i][r];
    }
    if (c + 1 < 32) {
      // outstanding: 3 V(c+1) loads (oldest) + 8 stores -> wait loads only
      asm volatile("s_waitcnt vmcnt(8)" ::: "memory");
      __builtin_amdgcn_s_barrier();
    }
  }
}

extern "C" void kernel_launch(void* const* d_in, const int* in_sizes, int n_in,
                              void* d_out, int out_size, void* d_ws, size_t ws_size,
                              hipStream_t stream) {
  const float* x  = (const float*)d_in[0];
  const float* Wq = (const float*)d_in[1];
  const float* bq = (const float*)d_in[2];
  const float* Wk = (const float*)d_in[3];
  const float* bk = (const float*)d_in[4];
  const float* Wv = (const float*)d_in[5];
  const float* bv = (const float*)d_in[6];
  float* out = (float*)d_out;

  _Float16* ws = (_Float16*)d_ws;
  _Float16* xh = ws;                    // 33554432
  _Float16* wt = ws + 33554432;         // 3145728
  _Float16* qh = ws + 36700160;         // 33554432
  _Float16* kh = ws + 70254592;         // 33554432
  _Float16* v8 = ws + 103809024;        // 33554432

  k_cvt_x<<<16384, 256, 0, stream>>>(x, xh);
  k_cvt_w<<<dim3(16, 16, 3), 256, 0, stream>>>(Wq, Wk, Wv, wt);
  k_gemm_qkv<<<dim3(1536), 512, 0, stream>>>(xh, wt, bq, bk, bv, qh, kh, v8);
  k_attn<<<dim3(32, 8), 512, 0, stream>>>(qh, kh, v8, out);
}